// Round 1
// baseline (1656.167 us; speedup 1.0000x reference)
//
#include <hip/hip_runtime.h>

#define DF 128

// ---------------------------------------------------------------------------
// Edge scatter: aggr[dst] += x[src], 32 lanes per edge, float4 per lane,
// 4 scalar f32 atomics per lane. Baseline (atomic-bound) implementation.
// ---------------------------------------------------------------------------
__global__ __launch_bounds__(256) void scatter_kernel(
    const float* __restrict__ x, const int* __restrict__ src,
    const int* __restrict__ dst, float* __restrict__ aggr, int n_edges)
{
    long long t = (long long)blockIdx.x * blockDim.x + threadIdx.x;
    int e    = (int)(t >> 5);
    int lane = (int)(t & 31);
    if (e >= n_edges) return;
    int s = src[e];
    int d = dst[e];
    float4 v = reinterpret_cast<const float4*>(x)[(size_t)s * 32 + lane];
    float* a = aggr + (size_t)d * DF + lane * 4;
    atomicAdd(a + 0, v.x);
    atomicAdd(a + 1, v.y);
    atomicAdd(a + 2, v.z);
    atomicAdd(a + 3, v.w);
}

// ---------------------------------------------------------------------------
// Fused output GEMM: out[n,o] = sum_d x[n,d]*W1[o,d] + aggr[n,d]*W2[o,d]
//                              + b1[o] + b2[o]
// Block = 256 threads, 32 nodes/block. W1,W2 staged in LDS (64 KB each).
// Thread (tx,ty): tx in [0,32) -> o-tile of 4, ty in [0,8) -> n-tile of 4.
// All lanes in a wave read the same LDS/W address per step -> broadcast, free.
// ---------------------------------------------------------------------------
__global__ __launch_bounds__(256) void gemm_kernel(
    const float* __restrict__ x, const float* __restrict__ aggr,
    const float* __restrict__ W1, const float* __restrict__ b1,
    const float* __restrict__ W2, const float* __restrict__ b2,
    float* __restrict__ out, int n_nodes)
{
    __shared__ float4 sW1[DF * 32];  // 64 KB: W1[o][d] as float4 chunks over d
    __shared__ float4 sW2[DF * 32];  // 64 KB

    const float4* W1v = reinterpret_cast<const float4*>(W1);
    const float4* W2v = reinterpret_cast<const float4*>(W2);
    for (int i = threadIdx.x; i < DF * 32; i += 256) {
        sW1[i] = W1v[i];
        sW2[i] = W2v[i];
    }
    __syncthreads();

    int tx = threadIdx.x & 31;   // o-tile index
    int ty = threadIdx.x >> 5;   // n-tile index
    int o0 = tx * 4;
    int nbase = blockIdx.x * 32 + ty * 4;

    int nidx[4];
#pragma unroll
    for (int i = 0; i < 4; ++i) {
        int n = nbase + i;
        nidx[i] = (n < n_nodes) ? n : (n_nodes - 1);  // clamp reads; writes guarded
    }

    const float4* xv = reinterpret_cast<const float4*>(x);
    const float4* av = reinterpret_cast<const float4*>(aggr);

    float acc[4][4] = {};

    for (int dv = 0; dv < 32; ++dv) {
        float4 xr[4], ar[4];
#pragma unroll
        for (int i = 0; i < 4; ++i) {
            xr[i] = xv[(size_t)nidx[i] * 32 + dv];
            ar[i] = av[(size_t)nidx[i] * 32 + dv];
        }
#pragma unroll
        for (int j = 0; j < 4; ++j) {
            float4 w1 = sW1[(o0 + j) * 32 + dv];
            float4 w2 = sW2[(o0 + j) * 32 + dv];
#pragma unroll
            for (int i = 0; i < 4; ++i) {
                acc[i][j] += xr[i].x * w1.x + xr[i].y * w1.y
                           + xr[i].z * w1.z + xr[i].w * w1.w
                           + ar[i].x * w2.x + ar[i].y * w2.y
                           + ar[i].z * w2.z + ar[i].w * w2.w;
            }
        }
    }

#pragma unroll
    for (int j = 0; j < 4; ++j) {
        float bias = b1[o0 + j] + b2[o0 + j];
#pragma unroll
        for (int i = 0; i < 4; ++i) {
            int n = nbase + i;
            if (n < n_nodes) out[(size_t)n * DF + o0 + j] = acc[i][j] + bias;
        }
    }
}

extern "C" void kernel_launch(void* const* d_in, const int* in_sizes, int n_in,
                              void* d_out, int out_size, void* d_ws, size_t ws_size,
                              hipStream_t stream) {
    const float* x  = (const float*)d_in[0];
    const float* W1 = (const float*)d_in[1];
    const float* b1 = (const float*)d_in[2];
    const float* W2 = (const float*)d_in[3];
    const float* b2 = (const float*)d_in[4];
    const int* esrc = (const int*)d_in[5];
    const int* edst = (const int*)d_in[6];
    float* out = (float*)d_out;

    int n_nodes = in_sizes[0] / DF;
    int n_edges = in_sizes[5];

    float* aggr = (float*)d_ws;  // n_nodes * DF floats = 25.6 MB scratch

    // d_ws is re-poisoned to 0xAA before every timed call -> must zero here.
    hipMemsetAsync(aggr, 0, (size_t)n_nodes * DF * sizeof(float), stream);

    {
        long long threads = (long long)n_edges * 32;
        int blocks = (int)((threads + 255) / 256);
        scatter_kernel<<<blocks, 256, 0, stream>>>(x, esrc, edst, aggr, n_edges);
    }
    {
        int blocks = (n_nodes + 31) / 32;
        gemm_kernel<<<blocks, 256, 0, stream>>>(x, aggr, W1, b1, W2, b2, out, n_nodes);
    }
}

// Round 2
// 566.778 us; speedup vs baseline: 2.9221x; 2.9221x over previous
//
#include <hip/hip_runtime.h>

#define DF 128

// ---------------------------------------------------------------------------
// CSR build: counting sort of edges by dst.
// ---------------------------------------------------------------------------
__global__ __launch_bounds__(256) void count_kernel(
    const int* __restrict__ dst, int* __restrict__ cnt, int n_edges)
{
    int e = blockIdx.x * 256 + threadIdx.x;
    if (e < n_edges) atomicAdd(&cnt[dst[e]], 1);
}

// Single-block exclusive scan over n counts. cnt is read then overwritten
// with the exclusive prefix (becomes the mutable fill cursor `pos`);
// offs[i] gets the same prefix, offs[n] = total.
__global__ __launch_bounds__(1024) void scan_kernel(
    int* __restrict__ cnt, int* __restrict__ offs, int n)
{
    __shared__ int sdata[1024];
    int t = threadIdx.x;
    int chunk = (n + 1023) / 1024;
    int lo = t * chunk;
    int hi = lo + chunk; if (hi > n) hi = n;
    int s = 0;
    for (int i = lo; i < hi; ++i) s += cnt[i];
    sdata[t] = s;
    __syncthreads();
    for (int off = 1; off < 1024; off <<= 1) {
        int v = 0;
        if (t >= off) v = sdata[t - off];
        __syncthreads();
        if (t >= off) sdata[t] += v;
        __syncthreads();
    }
    int total = sdata[1023];
    int run = (t > 0) ? sdata[t - 1] : 0;
    for (int i = lo; i < hi; ++i) {
        int c = cnt[i];
        offs[i] = run;
        cnt[i]  = run;   // fill cursor
        run += c;
    }
    if (t == 0) offs[n] = total;
}

__global__ __launch_bounds__(256) void fill_kernel(
    const int* __restrict__ src, const int* __restrict__ dst,
    int* __restrict__ pos, int* __restrict__ eidx, int n_edges)
{
    int e = blockIdx.x * 256 + threadIdx.x;
    if (e < n_edges) {
        int p = atomicAdd(&pos[dst[e]], 1);
        eidx[p] = src[e];
    }
}

// ---------------------------------------------------------------------------
// Gather aggregation: one wave (64 lanes) per dst node, float2 per lane.
// Register accumulate, single write, zero atomics.
// ---------------------------------------------------------------------------
__global__ __launch_bounds__(256) void aggregate_kernel(
    const float* __restrict__ x, const int* __restrict__ offs,
    const int* __restrict__ eidx, float* __restrict__ aggr, int n_nodes)
{
    int wave = threadIdx.x >> 6;
    int lane = threadIdx.x & 63;
    int node = blockIdx.x * 4 + wave;
    if (node >= n_nodes) return;

    int e0 = offs[node];
    int e1 = offs[node + 1];

    const float2* xv = reinterpret_cast<const float2*>(x);
    float2 acc = make_float2(0.f, 0.f);

    int e = e0;
    for (; e + 1 < e1; e += 2) {   // 2 outstanding gathers for MLP
        int s0 = eidx[e];
        int s1 = eidx[e + 1];
        float2 v0 = xv[(size_t)s0 * 64 + lane];
        float2 v1 = xv[(size_t)s1 * 64 + lane];
        acc.x += v0.x; acc.y += v0.y;
        acc.x += v1.x; acc.y += v1.y;
    }
    if (e < e1) {
        int s0 = eidx[e];
        float2 v0 = xv[(size_t)s0 * 64 + lane];
        acc.x += v0.x; acc.y += v0.y;
    }
    reinterpret_cast<float2*>(aggr)[(size_t)node * 64 + lane] = acc;
}

// ---------------------------------------------------------------------------
// Fused output GEMM (unchanged from R1): out = x@W1^T + aggr@W2^T + b1 + b2
// ---------------------------------------------------------------------------
__global__ __launch_bounds__(256) void gemm_kernel(
    const float* __restrict__ x, const float* __restrict__ aggr,
    const float* __restrict__ W1, const float* __restrict__ b1,
    const float* __restrict__ W2, const float* __restrict__ b2,
    float* __restrict__ out, int n_nodes)
{
    __shared__ float4 sW1[DF * 32];
    __shared__ float4 sW2[DF * 32];

    const float4* W1v = reinterpret_cast<const float4*>(W1);
    const float4* W2v = reinterpret_cast<const float4*>(W2);
    for (int i = threadIdx.x; i < DF * 32; i += 256) {
        sW1[i] = W1v[i];
        sW2[i] = W2v[i];
    }
    __syncthreads();

    int tx = threadIdx.x & 31;
    int ty = threadIdx.x >> 5;
    int o0 = tx * 4;
    int nbase = blockIdx.x * 32 + ty * 4;

    int nidx[4];
#pragma unroll
    for (int i = 0; i < 4; ++i) {
        int n = nbase + i;
        nidx[i] = (n < n_nodes) ? n : (n_nodes - 1);
    }

    const float4* xv = reinterpret_cast<const float4*>(x);
    const float4* av = reinterpret_cast<const float4*>(aggr);

    float acc[4][4] = {};

    for (int dv = 0; dv < 32; ++dv) {
        float4 xr[4], ar[4];
#pragma unroll
        for (int i = 0; i < 4; ++i) {
            xr[i] = xv[(size_t)nidx[i] * 32 + dv];
            ar[i] = av[(size_t)nidx[i] * 32 + dv];
        }
#pragma unroll
        for (int j = 0; j < 4; ++j) {
            float4 w1 = sW1[(o0 + j) * 32 + dv];
            float4 w2 = sW2[(o0 + j) * 32 + dv];
#pragma unroll
            for (int i = 0; i < 4; ++i) {
                acc[i][j] += xr[i].x * w1.x + xr[i].y * w1.y
                           + xr[i].z * w1.z + xr[i].w * w1.w
                           + ar[i].x * w2.x + ar[i].y * w2.y
                           + ar[i].z * w2.z + ar[i].w * w2.w;
            }
        }
    }

#pragma unroll
    for (int j = 0; j < 4; ++j) {
        float bias = b1[o0 + j] + b2[o0 + j];
#pragma unroll
        for (int i = 0; i < 4; ++i) {
            int n = nbase + i;
            if (n < n_nodes) out[(size_t)n * DF + o0 + j] = acc[i][j] + bias;
        }
    }
}

extern "C" void kernel_launch(void* const* d_in, const int* in_sizes, int n_in,
                              void* d_out, int out_size, void* d_ws, size_t ws_size,
                              hipStream_t stream) {
    const float* x  = (const float*)d_in[0];
    const float* W1 = (const float*)d_in[1];
    const float* b1 = (const float*)d_in[2];
    const float* W2 = (const float*)d_in[3];
    const float* b2 = (const float*)d_in[4];
    const int* esrc = (const int*)d_in[5];
    const int* edst = (const int*)d_in[6];
    float* out = (float*)d_out;

    int n_nodes = in_sizes[0] / DF;
    int n_edges = in_sizes[5];

    // Workspace layout:
    //   aggr : n_nodes*DF floats
    //   offs : n_nodes+1 ints
    //   pos  : n_nodes ints   (count buffer, then fill cursor)
    //   eidx : n_edges ints
    char* ws = (char*)d_ws;
    float* aggr = (float*)ws;
    size_t aggr_bytes = (size_t)n_nodes * DF * sizeof(float);
    int* offs = (int*)(ws + aggr_bytes);
    int* pos  = offs + (n_nodes + 1);
    int* eidx = pos + n_nodes;

    // zero the count buffer only (aggregate writes every node, no memset needed)
    hipMemsetAsync(pos, 0, (size_t)n_nodes * sizeof(int), stream);

    int eb = (n_edges + 255) / 256;
    count_kernel<<<eb, 256, 0, stream>>>(edst, pos, n_edges);
    scan_kernel<<<1, 1024, 0, stream>>>(pos, offs, n_nodes);
    fill_kernel<<<eb, 256, 0, stream>>>(esrc, edst, pos, eidx, n_edges);
    aggregate_kernel<<<(n_nodes + 3) / 4, 256, 0, stream>>>(x, offs, eidx, aggr, n_nodes);
    gemm_kernel<<<(n_nodes + 31) / 32, 256, 0, stream>>>(x, aggr, W1, b1, W2, b2, out, n_nodes);
}

// Round 3
// 355.300 us; speedup vs baseline: 4.6613x; 1.5952x over previous
//
#include <hip/hip_runtime.h>
#include <hip/hip_bf16.h>

#define DF 128

typedef __attribute__((ext_vector_type(8))) short short8;
typedef __attribute__((ext_vector_type(4))) float floatx4;

__device__ __forceinline__ ushort f2bf(float f) {
    __hip_bfloat16 h = __float2bfloat16(f);   // RNE
    return *reinterpret_cast<ushort*>(&h);
}

// ---------------------------------------------------------------------------
// x (fp32) -> xbf (bf16), 4 elements/thread
// ---------------------------------------------------------------------------
__global__ __launch_bounds__(256) void convert_x_kernel(
    const float* __restrict__ x, ushort* __restrict__ xbf, int n4)
{
    int i = blockIdx.x * 256 + threadIdx.x;
    if (i >= n4) return;
    float4 v = reinterpret_cast<const float4*>(x)[i];
    ushort4 o;
    o.x = f2bf(v.x); o.y = f2bf(v.y); o.z = f2bf(v.z); o.w = f2bf(v.w);
    reinterpret_cast<ushort4*>(xbf)[i] = o;
}

// W1,W2 (fp32) -> bf16; bias = b1+b2 (fp32). 64 blocks x 256.
__global__ __launch_bounds__(256) void convert_w_kernel(
    const float* __restrict__ W1, const float* __restrict__ W2,
    const float* __restrict__ b1, const float* __restrict__ b2,
    ushort* __restrict__ w1bf, ushort* __restrict__ w2bf,
    float* __restrict__ bias)
{
    int i = blockIdx.x * 256 + threadIdx.x;
    if (i < DF * DF) {
        w1bf[i] = f2bf(W1[i]);
        w2bf[i] = f2bf(W2[i]);
    }
    if (i < DF) bias[i] = b1[i] + b2[i];
}

// ---------------------------------------------------------------------------
// CSR build: counting sort of edges by dst.
// ---------------------------------------------------------------------------
__global__ __launch_bounds__(256) void count_kernel(
    const int* __restrict__ dst, int* __restrict__ cnt, int n_edges)
{
    int e = blockIdx.x * 256 + threadIdx.x;
    if (e < n_edges) atomicAdd(&cnt[dst[e]], 1);
}

__global__ __launch_bounds__(1024) void scan_kernel(
    int* __restrict__ cnt, int* __restrict__ offs, int n)
{
    __shared__ int sdata[1024];
    int t = threadIdx.x;
    int chunk = (n + 1023) / 1024;
    int lo = t * chunk;
    int hi = lo + chunk; if (hi > n) hi = n;
    int s = 0;
    for (int i = lo; i < hi; ++i) s += cnt[i];
    sdata[t] = s;
    __syncthreads();
    for (int off = 1; off < 1024; off <<= 1) {
        int v = 0;
        if (t >= off) v = sdata[t - off];
        __syncthreads();
        if (t >= off) sdata[t] += v;
        __syncthreads();
    }
    int total = sdata[1023];
    int run = (t > 0) ? sdata[t - 1] : 0;
    for (int i = lo; i < hi; ++i) {
        int c = cnt[i];
        offs[i] = run;
        cnt[i]  = run;   // becomes fill cursor
        run += c;
    }
    if (t == 0) offs[n] = total;
}

__global__ __launch_bounds__(256) void fill_kernel(
    const int* __restrict__ src, const int* __restrict__ dst,
    int* __restrict__ pos, int* __restrict__ eidx, int n_edges)
{
    int e = blockIdx.x * 256 + threadIdx.x;
    if (e < n_edges) {
        int p = atomicAdd(&pos[dst[e]], 1);
        eidx[p] = src[e];
    }
}

// ---------------------------------------------------------------------------
// Gather aggregation (bf16 in, bf16 out, fp32 accumulate).
// One wave per dst node, 2 bf16 (one uint) per lane.
// ---------------------------------------------------------------------------
__global__ __launch_bounds__(256) void aggregate_kernel(
    const ushort* __restrict__ xbf, const int* __restrict__ offs,
    const int* __restrict__ eidx, ushort* __restrict__ aggr, int n_nodes)
{
    int wave = threadIdx.x >> 6;
    int lane = threadIdx.x & 63;
    int node = blockIdx.x * 4 + wave;
    if (node >= n_nodes) return;

    int e0 = offs[node];
    int e1 = offs[node + 1];

    const uint* xv = reinterpret_cast<const uint*>(xbf);
    float a0 = 0.f, a1 = 0.f;

    int e = e0;
    for (; e + 3 < e1; e += 4) {
        int s0 = eidx[e], s1 = eidx[e + 1], s2 = eidx[e + 2], s3 = eidx[e + 3];
        uint u0 = xv[(size_t)s0 * 64 + lane];
        uint u1 = xv[(size_t)s1 * 64 + lane];
        uint u2 = xv[(size_t)s2 * 64 + lane];
        uint u3 = xv[(size_t)s3 * 64 + lane];
        a0 += __uint_as_float(u0 << 16) + __uint_as_float(u1 << 16)
            + __uint_as_float(u2 << 16) + __uint_as_float(u3 << 16);
        a1 += __uint_as_float(u0 & 0xffff0000u) + __uint_as_float(u1 & 0xffff0000u)
            + __uint_as_float(u2 & 0xffff0000u) + __uint_as_float(u3 & 0xffff0000u);
    }
    for (; e < e1; ++e) {
        uint u = xv[(size_t)eidx[e] * 64 + lane];
        a0 += __uint_as_float(u << 16);
        a1 += __uint_as_float(u & 0xffff0000u);
    }
    uint packed = (uint)f2bf(a0) | ((uint)f2bf(a1) << 16);
    reinterpret_cast<uint*>(aggr)[(size_t)node * 64 + lane] = packed;
}

// ---------------------------------------------------------------------------
// Fused MFMA GEMM: out[n,o] = x@W1^T + aggr@W2^T + (b1+b2)
// mfma_f32_16x16x32_bf16. A-frag = 8 contiguous bf16 of x[n,:];
// B-frag = 8 contiguous bf16 of W[o,:]. No LDS, no repack.
// Wave handles 16 nodes x 128 outputs; block = 4 waves = 64 nodes.
// ---------------------------------------------------------------------------
__global__ __launch_bounds__(256) void mfma_gemm_kernel(
    const ushort* __restrict__ xbf, const ushort* __restrict__ abf,
    const ushort* __restrict__ w1, const ushort* __restrict__ w2,
    const float* __restrict__ bias, float* __restrict__ out, int n_nodes)
{
    int wave = threadIdx.x >> 6;
    int lane = threadIdx.x & 63;
    int n0 = blockIdx.x * 64 + wave * 16;
    if (n0 >= n_nodes) return;

    int quad = lane >> 4;
    int m    = lane & 15;

    int arow = n0 + m;
    if (arow >= n_nodes) arow = n_nodes - 1;   // clamp loads; stores guarded

    short8 xa[4], aa[4];
#pragma unroll
    for (int ks = 0; ks < 4; ++ks) {
        xa[ks] = *reinterpret_cast<const short8*>(xbf + (size_t)arow * DF + ks * 32 + quad * 8);
        aa[ks] = *reinterpret_cast<const short8*>(abf + (size_t)arow * DF + ks * 32 + quad * 8);
    }

#pragma unroll
    for (int ot = 0; ot < 8; ++ot) {
        int o = ot * 16 + m;   // B column this lane feeds / output col this lane writes
        floatx4 c = {0.f, 0.f, 0.f, 0.f};
#pragma unroll
        for (int ks = 0; ks < 4; ++ks) {
            short8 bf1 = *reinterpret_cast<const short8*>(w1 + (size_t)o * DF + ks * 32 + quad * 8);
            short8 bf2 = *reinterpret_cast<const short8*>(w2 + (size_t)o * DF + ks * 32 + quad * 8);
            c = __builtin_amdgcn_mfma_f32_16x16x32_bf16(xa[ks], bf1, c, 0, 0, 0);
            c = __builtin_amdgcn_mfma_f32_16x16x32_bf16(aa[ks], bf2, c, 0, 0, 0);
        }
        float bv = bias[o];
#pragma unroll
        for (int r = 0; r < 4; ++r) {
            int row = n0 + quad * 4 + r;
            if (row < n_nodes) out[(size_t)row * DF + o] = c[r] + bv;
        }
    }
}

extern "C" void kernel_launch(void* const* d_in, const int* in_sizes, int n_in,
                              void* d_out, int out_size, void* d_ws, size_t ws_size,
                              hipStream_t stream) {
    const float* x  = (const float*)d_in[0];
    const float* W1 = (const float*)d_in[1];
    const float* b1 = (const float*)d_in[2];
    const float* W2 = (const float*)d_in[3];
    const float* b2 = (const float*)d_in[4];
    const int* esrc = (const int*)d_in[5];
    const int* edst = (const int*)d_in[6];
    float* out = (float*)d_out;

    int n_nodes = in_sizes[0] / DF;
    int n_edges = in_sizes[5];

    // Workspace layout (16B-aligned chunks):
    //   xbf   : n_nodes*DF bf16            (12.8 MB)
    //   aggrb : n_nodes*DF bf16            (12.8 MB)
    //   w1bf  : DF*DF bf16                 (32 KB)
    //   w2bf  : DF*DF bf16                 (32 KB)
    //   bias  : DF fp32                    (512 B)
    //   offs  : n_nodes+1 int
    //   pos   : n_nodes int
    //   eidx  : n_edges int
    char* ws = (char*)d_ws;
    ushort* xbf   = (ushort*)ws;                 ws += (size_t)n_nodes * DF * 2;
    ushort* aggrb = (ushort*)ws;                 ws += (size_t)n_nodes * DF * 2;
    ushort* w1bf  = (ushort*)ws;                 ws += (size_t)DF * DF * 2;
    ushort* w2bf  = (ushort*)ws;                 ws += (size_t)DF * DF * 2;
    float*  bias  = (float*)ws;                  ws += (size_t)DF * 4;
    int*    offs  = (int*)ws;                    ws += (size_t)(n_nodes + 1) * 4;
    int*    pos   = (int*)ws;                    ws += (size_t)n_nodes * 4;
    int*    eidx  = (int*)ws;

    hipMemsetAsync(pos, 0, (size_t)n_nodes * sizeof(int), stream);

    int n4 = n_nodes * DF / 4;
    convert_x_kernel<<<(n4 + 255) / 256, 256, 0, stream>>>(x, xbf, n4);
    convert_w_kernel<<<(DF * DF + 255) / 256, 256, 0, stream>>>(W1, W2, b1, b2, w1bf, w2bf, bias);

    int eb = (n_edges + 255) / 256;
    count_kernel<<<eb, 256, 0, stream>>>(edst, pos, n_edges);
    scan_kernel<<<1, 1024, 0, stream>>>(pos, offs, n_nodes);
    fill_kernel<<<eb, 256, 0, stream>>>(esrc, edst, pos, eidx, n_edges);

    aggregate_kernel<<<(n_nodes + 3) / 4, 256, 0, stream>>>(xbf, offs, eidx, aggrb, n_nodes);
    mfma_gemm_kernel<<<(n_nodes + 63) / 64, 256, 0, stream>>>(xbf, aggrb, w1bf, w2bf, bias, out, n_nodes);
}

// Round 4
// 262.621 us; speedup vs baseline: 6.3063x; 1.3529x over previous
//
#include <hip/hip_runtime.h>
#include <hip/hip_bf16.h>

#define DF 128

typedef __attribute__((ext_vector_type(8))) short short8;
typedef __attribute__((ext_vector_type(4))) float floatx4;

__device__ __forceinline__ ushort f2bf(float f) {
    __hip_bfloat16 h = __float2bfloat16(f);   // RNE
    return *reinterpret_cast<ushort*>(&h);
}

// ---------------------------------------------------------------------------
// x (fp32) -> xbf (bf16), 4 elements/thread
// ---------------------------------------------------------------------------
__global__ __launch_bounds__(256) void convert_x_kernel(
    const float* __restrict__ x, ushort* __restrict__ xbf, int n4)
{
    int i = blockIdx.x * 256 + threadIdx.x;
    if (i >= n4) return;
    float4 v = reinterpret_cast<const float4*>(x)[i];
    ushort4 o;
    o.x = f2bf(v.x); o.y = f2bf(v.y); o.z = f2bf(v.z); o.w = f2bf(v.w);
    reinterpret_cast<ushort4*>(xbf)[i] = o;
}

__global__ __launch_bounds__(256) void convert_w_kernel(
    const float* __restrict__ W1, const float* __restrict__ W2,
    const float* __restrict__ b1, const float* __restrict__ b2,
    ushort* __restrict__ w1bf, ushort* __restrict__ w2bf,
    float* __restrict__ bias)
{
    int i = blockIdx.x * 256 + threadIdx.x;
    if (i < DF * DF) {
        w1bf[i] = f2bf(W1[i]);
        w2bf[i] = f2bf(W2[i]);
    }
    if (i < DF) bias[i] = b1[i] + b2[i];
}

// ---------------------------------------------------------------------------
// CSR build: counting sort of edges by dst.
// ---------------------------------------------------------------------------
__global__ __launch_bounds__(256) void count_kernel(
    const int* __restrict__ dst, int* __restrict__ cnt, int n_edges)
{
    int e = blockIdx.x * 256 + threadIdx.x;
    if (e < n_edges) atomicAdd(&cnt[dst[e]], 1);
}

// ---------------------------------------------------------------------------
// Hierarchical exclusive scan (3 phases, fully parallel).
// Phase A: 1024 counts/block, int4 per thread, LDS block scan.
//          offs gets block-LOCAL exclusive prefixes; bsum[b] = block total.
// ---------------------------------------------------------------------------
__global__ __launch_bounds__(256) void scan_local_kernel(
    const int* __restrict__ cnt, int* __restrict__ offs,
    int* __restrict__ bsum, int n)
{
    __shared__ int sd[256];
    int t = threadIdx.x;
    int base = blockIdx.x * 1024 + t * 4;

    int4 v = make_int4(0, 0, 0, 0);
    if (base + 3 < n) {
        v = *reinterpret_cast<const int4*>(cnt + base);
    } else {
        if (base + 0 < n) v.x = cnt[base + 0];
        if (base + 1 < n) v.y = cnt[base + 1];
        if (base + 2 < n) v.z = cnt[base + 2];
        if (base + 3 < n) v.w = cnt[base + 3];
    }
    int s = v.x + v.y + v.z + v.w;
    sd[t] = s;
    __syncthreads();
    for (int off = 1; off < 256; off <<= 1) {
        int u = (t >= off) ? sd[t - off] : 0;
        __syncthreads();
        sd[t] += u;
        __syncthreads();
    }
    int incl = sd[t];
    int excl = incl - s;
    if (t == 255) bsum[blockIdx.x] = incl;

    int p0 = excl, p1 = p0 + v.x, p2 = p1 + v.y, p3 = p2 + v.z;
    if (base + 0 < n) offs[base + 0] = p0;
    if (base + 1 < n) offs[base + 1] = p1;
    if (base + 2 < n) offs[base + 2] = p2;
    if (base + 3 < n) offs[base + 3] = p3;
}

// Phase B: exclusive-scan the block totals (nb <= 1024) in place; offs[n]=total.
__global__ __launch_bounds__(1024) void scan_bsum_kernel(
    int* __restrict__ bsum, int* __restrict__ offs, int nb, int n)
{
    __shared__ int sd[1024];
    int t = threadIdx.x;
    int v = (t < nb) ? bsum[t] : 0;
    sd[t] = v;
    __syncthreads();
    for (int off = 1; off < 1024; off <<= 1) {
        int u = (t >= off) ? sd[t - off] : 0;
        __syncthreads();
        sd[t] += u;
        __syncthreads();
    }
    if (t < nb) bsum[t] = sd[t] - v;
    if (t == 1023) offs[n] = sd[1023];
}

// Phase C: add block base; materialize final offs and the fill cursor pos.
__global__ __launch_bounds__(256) void add_base_kernel(
    int* __restrict__ offs, int* __restrict__ pos,
    const int* __restrict__ bsum, int n)
{
    int b = blockIdx.x;
    int bb = bsum[b];
    int base = b * 1024 + threadIdx.x * 4;
#pragma unroll
    for (int i = 0; i < 4; ++i) {
        int idx = base + i;
        if (idx < n) {
            int o = offs[idx] + bb;
            offs[idx] = o;
            pos[idx]  = o;
        }
    }
}

__global__ __launch_bounds__(256) void fill_kernel(
    const int* __restrict__ src, const int* __restrict__ dst,
    int* __restrict__ pos, int* __restrict__ eidx, int n_edges)
{
    int e = blockIdx.x * 256 + threadIdx.x;
    if (e < n_edges) {
        int p = atomicAdd(&pos[dst[e]], 1);
        eidx[p] = src[e];
    }
}

// ---------------------------------------------------------------------------
// Gather aggregation (bf16 in, bf16 out, fp32 accumulate).
// One wave per dst node, 2 bf16 (one uint) per lane.
// ---------------------------------------------------------------------------
__global__ __launch_bounds__(256) void aggregate_kernel(
    const ushort* __restrict__ xbf, const int* __restrict__ offs,
    const int* __restrict__ eidx, ushort* __restrict__ aggr, int n_nodes)
{
    int wave = threadIdx.x >> 6;
    int lane = threadIdx.x & 63;
    int node = blockIdx.x * 4 + wave;
    if (node >= n_nodes) return;

    int e0 = offs[node];
    int e1 = offs[node + 1];

    const uint* xv = reinterpret_cast<const uint*>(xbf);
    float a0 = 0.f, a1 = 0.f;

    int e = e0;
    for (; e + 3 < e1; e += 4) {
        int s0 = eidx[e], s1 = eidx[e + 1], s2 = eidx[e + 2], s3 = eidx[e + 3];
        uint u0 = xv[(size_t)s0 * 64 + lane];
        uint u1 = xv[(size_t)s1 * 64 + lane];
        uint u2 = xv[(size_t)s2 * 64 + lane];
        uint u3 = xv[(size_t)s3 * 64 + lane];
        a0 += __uint_as_float(u0 << 16) + __uint_as_float(u1 << 16)
            + __uint_as_float(u2 << 16) + __uint_as_float(u3 << 16);
        a1 += __uint_as_float(u0 & 0xffff0000u) + __uint_as_float(u1 & 0xffff0000u)
            + __uint_as_float(u2 & 0xffff0000u) + __uint_as_float(u3 & 0xffff0000u);
    }
    for (; e < e1; ++e) {
        uint u = xv[(size_t)eidx[e] * 64 + lane];
        a0 += __uint_as_float(u << 16);
        a1 += __uint_as_float(u & 0xffff0000u);
    }
    uint packed = (uint)f2bf(a0) | ((uint)f2bf(a1) << 16);
    reinterpret_cast<uint*>(aggr)[(size_t)node * 64 + lane] = packed;
}

// ---------------------------------------------------------------------------
// Fused MFMA GEMM: out[n,o] = x@W1^T + aggr@W2^T + (b1+b2)
// ---------------------------------------------------------------------------
__global__ __launch_bounds__(256) void mfma_gemm_kernel(
    const ushort* __restrict__ xbf, const ushort* __restrict__ abf,
    const ushort* __restrict__ w1, const ushort* __restrict__ w2,
    const float* __restrict__ bias, float* __restrict__ out, int n_nodes)
{
    int wave = threadIdx.x >> 6;
    int lane = threadIdx.x & 63;
    int n0 = blockIdx.x * 64 + wave * 16;
    if (n0 >= n_nodes) return;

    int quad = lane >> 4;
    int m    = lane & 15;

    int arow = n0 + m;
    if (arow >= n_nodes) arow = n_nodes - 1;   // clamp loads; stores guarded

    short8 xa[4], aa[4];
#pragma unroll
    for (int ks = 0; ks < 4; ++ks) {
        xa[ks] = *reinterpret_cast<const short8*>(xbf + (size_t)arow * DF + ks * 32 + quad * 8);
        aa[ks] = *reinterpret_cast<const short8*>(abf + (size_t)arow * DF + ks * 32 + quad * 8);
    }

#pragma unroll
    for (int ot = 0; ot < 8; ++ot) {
        int o = ot * 16 + m;
        floatx4 c = {0.f, 0.f, 0.f, 0.f};
#pragma unroll
        for (int ks = 0; ks < 4; ++ks) {
            short8 bf1 = *reinterpret_cast<const short8*>(w1 + (size_t)o * DF + ks * 32 + quad * 8);
            short8 bf2 = *reinterpret_cast<const short8*>(w2 + (size_t)o * DF + ks * 32 + quad * 8);
            c = __builtin_amdgcn_mfma_f32_16x16x32_bf16(xa[ks], bf1, c, 0, 0, 0);
            c = __builtin_amdgcn_mfma_f32_16x16x32_bf16(aa[ks], bf2, c, 0, 0, 0);
        }
        float bv = bias[o];
#pragma unroll
        for (int r = 0; r < 4; ++r) {
            int row = n0 + quad * 4 + r;
            if (row < n_nodes) out[(size_t)row * DF + o] = c[r] + bv;
        }
    }
}

extern "C" void kernel_launch(void* const* d_in, const int* in_sizes, int n_in,
                              void* d_out, int out_size, void* d_ws, size_t ws_size,
                              hipStream_t stream) {
    const float* x  = (const float*)d_in[0];
    const float* W1 = (const float*)d_in[1];
    const float* b1 = (const float*)d_in[2];
    const float* W2 = (const float*)d_in[3];
    const float* b2 = (const float*)d_in[4];
    const int* esrc = (const int*)d_in[5];
    const int* edst = (const int*)d_in[6];
    float* out = (float*)d_out;

    int n_nodes = in_sizes[0] / DF;
    int n_edges = in_sizes[5];

    // Workspace layout:
    //   xbf   : n_nodes*DF bf16
    //   aggrb : n_nodes*DF bf16
    //   w1bf, w2bf : DF*DF bf16 each
    //   bias  : DF fp32
    //   offs  : n_nodes+1 int
    //   pos   : n_nodes int
    //   cnt   : n_nodes int
    //   bsum  : 1024 int
    //   eidx  : n_edges int
    char* ws = (char*)d_ws;
    ushort* xbf   = (ushort*)ws;                 ws += (size_t)n_nodes * DF * 2;
    ushort* aggrb = (ushort*)ws;                 ws += (size_t)n_nodes * DF * 2;
    ushort* w1bf  = (ushort*)ws;                 ws += (size_t)DF * DF * 2;
    ushort* w2bf  = (ushort*)ws;                 ws += (size_t)DF * DF * 2;
    float*  bias  = (float*)ws;                  ws += (size_t)DF * 4;
    int*    offs  = (int*)ws;                    ws += (size_t)(n_nodes + 1) * 4;
    int*    pos   = (int*)ws;                    ws += (size_t)n_nodes * 4;
    int*    cnt   = (int*)ws;                    ws += (size_t)n_nodes * 4;
    int*    bsum  = (int*)ws;                    ws += 1024 * 4;
    int*    eidx  = (int*)ws;

    hipMemsetAsync(cnt, 0, (size_t)n_nodes * sizeof(int), stream);

    int n4 = n_nodes * DF / 4;
    convert_x_kernel<<<(n4 + 255) / 256, 256, 0, stream>>>(x, xbf, n4);
    convert_w_kernel<<<(DF * DF + 255) / 256, 256, 0, stream>>>(W1, W2, b1, b2, w1bf, w2bf, bias);

    int eb = (n_edges + 255) / 256;
    count_kernel<<<eb, 256, 0, stream>>>(edst, cnt, n_edges);

    int nb = (n_nodes + 1023) / 1024;   // blocks in hierarchical scan (<=1024)
    scan_local_kernel<<<nb, 256, 0, stream>>>(cnt, offs, bsum, n_nodes);
    scan_bsum_kernel<<<1, 1024, 0, stream>>>(bsum, offs, nb, n_nodes);
    add_base_kernel<<<nb, 256, 0, stream>>>(offs, pos, bsum, n_nodes);

    fill_kernel<<<eb, 256, 0, stream>>>(esrc, edst, pos, eidx, n_edges);

    aggregate_kernel<<<(n_nodes + 3) / 4, 256, 0, stream>>>(xbf, offs, eidx, aggrb, n_nodes);
    mfma_gemm_kernel<<<(n_nodes + 63) / 64, 256, 0, stream>>>(xbf, aggrb, w1bf, w2bf, bias, out, n_nodes);
}